// Round 5
// baseline (952.492 us; speedup 1.0000x reference)
//
#include <hip/hip_runtime.h>
#include <stdint.h>

typedef short short8 __attribute__((ext_vector_type(8)));
typedef float f32x4 __attribute__((ext_vector_type(4)));

#define N_NODES 8192
#define IN_DIM 20000
#define HIDDEN 256
#define LATENT 64
#define N_EDGES 262144
#define K_STEPS 625
#define RECON_ELEMS (8192LL * 20000LL)
#define NSUB3 626   // 32-col subtiles covering 20032 >= 20000 cols

static __device__ __forceinline__ unsigned short f2bf(float f) {
  union { float f; unsigned int u; } v;
  v.f = f;
  unsigned int u = v.u;
  return (unsigned short)((u + 0x7FFFu + ((u >> 16) & 1u)) >> 16);  // RNE
}

static __device__ __forceinline__ unsigned pk2bf(float a, float b) {
  return (unsigned)f2bf(a) | ((unsigned)f2bf(b) << 16);
}

// ----------------- graph prep: degree, scan, CSR fill -----------------
__global__ void k_count(const int* __restrict__ col, int* __restrict__ cnt) {
  int e = blockIdx.x * 256 + threadIdx.x;
  if (e < N_EDGES) atomicAdd(&cnt[col[e]], 1);
}

__global__ void k_dinv(const int* __restrict__ cnt, float* __restrict__ dinv) {
  int i = blockIdx.x * 256 + threadIdx.x;
  if (i < N_NODES) dinv[i] = rsqrtf((float)(cnt[i] + 1));  // +1 self loop
}

__global__ void k_scan(const int* __restrict__ cnt, int* __restrict__ offs,
                       int* __restrict__ cursor) {
  __shared__ int ps[256];
  int t = threadIdx.x;
  int local[32];
  int s = 0;
#pragma unroll
  for (int i = 0; i < 32; ++i) { local[i] = cnt[t * 32 + i]; s += local[i]; }
  ps[t] = s;
  __syncthreads();
  for (int d = 1; d < 256; d <<= 1) {
    int v = (t >= d) ? ps[t - d] : 0;
    __syncthreads();
    ps[t] += v;
    __syncthreads();
  }
  int pre = (t == 0) ? 0 : ps[t - 1];
#pragma unroll
  for (int i = 0; i < 32; ++i) {
    offs[t * 32 + i] = pre;
    cursor[t * 32 + i] = pre;
    pre += local[i];
  }
  if (t == 255) offs[N_NODES] = pre;
}

__global__ void k_fill(const int* __restrict__ row, const int* __restrict__ col,
                       int* __restrict__ cursor, int* __restrict__ csr_src) {
  int e = blockIdx.x * 256 + threadIdx.x;
  if (e < N_EDGES) {
    int c = col[e];
    int pos = atomicAdd(&cursor[c], 1);
    csr_src[pos] = row[e];
  }
}

// ------- pack w_gcn [20000][256] f32 -> [kstep][n=256][k=32] bf16 (linear) ---
__global__ void k_pack_wgcn(const float* __restrict__ w, unsigned short* __restrict__ pk) {
  int s = blockIdx.x;   // 625 k-steps
  int t = threadIdx.x;  // n = t
  int k0 = s * 32;
  unsigned int packed[16];
#pragma unroll
  for (int j = 0; j < 16; ++j) {
    float a = w[(size_t)(k0 + 2 * j) * HIDDEN + t];
    float b = w[(size_t)(k0 + 2 * j + 1) * HIDDEN + t];
    packed[j] = pk2bf(a, b);
  }
  uint4* dst = (uint4*)(pk + ((size_t)s * HIDDEN + t) * 32);
#pragma unroll
  for (int j = 0; j < 4; ++j)
    dst[j] = make_uint4(packed[4 * j], packed[4 * j + 1], packed[4 * j + 2], packed[4 * j + 3]);
}

// ------- pack w_d2 [256][20000] f32 -> fragment-major wd2f:
// ------- wd2f[((sub*8 + ks)*32 + c)*32 + kk] = bf16(w_d2[ks*32+kk][sub*32+c])
__global__ void k_pack_wd2f(const float* __restrict__ wd2, unsigned short* __restrict__ wd2f) {
  __shared__ float tile[HIDDEN * 32];  // [k][c], 32 KB
  int sub = blockIdx.x;   // 626
  int t = threadIdx.x;    // 256
  int c = t & 31;
  int ko = t >> 5;        // 0..7
  int gn = sub * 32 + c;
#pragma unroll 8
  for (int kk = 0; kk < 32; ++kk) {
    int k = kk * 8 + ko;
    tile[k * 32 + c] = (gn < IN_DIM) ? wd2[(size_t)k * IN_DIM + gn] : 0.0f;
  }
  __syncthreads();
  unsigned pkd[16];
#pragma unroll
  for (int lg = 0; lg < 4; ++lg)
#pragma unroll
    for (int j = 0; j < 4; ++j)
      pkd[lg * 4 + j] = pk2bf(tile[(ko * 32 + lg * 8 + 2 * j) * 32 + c],
                              tile[(ko * 32 + lg * 8 + 2 * j + 1) * 32 + c]);
  uint4* dst = (uint4*)(wd2f + ((size_t)(sub * 8 + ko) * 32 + c) * 32);
#pragma unroll
  for (int q = 0; q < 4; ++q)
    dst[q] = make_uint4(pkd[4 * q], pkd[4 * q + 1], pkd[4 * q + 2], pkd[4 * q + 3]);
}

// ----------------- GEMM1: h0p[split] = x @ w_gcn (bf16 MFMA) -----------------
// BM=32 BN=256 BK=32, split-K=4, grid (256,4), 256 thr (4 waves on N).
// NO LDS, NO barriers: A and B fragments direct from global into regs,
// one-deep prefetch; free-running waves hide HBM latency.
__global__ __launch_bounds__(256, 4)
void k_gemm1(const float* __restrict__ x, const unsigned short* __restrict__ wpk,
             float* __restrict__ h0p) {
  const int m0 = blockIdx.x * 32;
  const int split = blockIdx.y;
  const int s_beg = (K_STEPS * split) >> 2;
  const int s_end = (K_STEPS * (split + 1)) >> 2;

  const int t = threadIdx.x;
  const int lane = t & 63;
  const int wn = t >> 6;     // 0..3: 64-col group
  const int lr = lane & 15;
  const int lg = lane >> 4;

  const float* arow0 = x + (size_t)(m0 + lr) * IN_DIM + lg * 8;
  const float* arow1 = x + (size_t)(m0 + 16 + lr) * IN_DIM + lg * 8;
  const unsigned short* bp = wpk + ((size_t)s_beg * HIDDEN + wn * 64 + lr) * 32 + lg * 8;

  f32x4 acc[2][4];
#pragma unroll
  for (int i = 0; i < 2; ++i)
#pragma unroll
    for (int j = 0; j < 4; ++j) acc[i][j] = (f32x4){0.f, 0.f, 0.f, 0.f};

  float4 u0 = *(const float4*)(arow0 + (size_t)s_beg * 32);
  float4 u1 = *(const float4*)(arow0 + (size_t)s_beg * 32 + 4);
  float4 u2 = *(const float4*)(arow1 + (size_t)s_beg * 32);
  float4 u3 = *(const float4*)(arow1 + (size_t)s_beg * 32 + 4);
  short8 bc[4];
#pragma unroll
  for (int nt = 0; nt < 4; ++nt) bc[nt] = *(const short8*)(bp + nt * 512);

  for (int s = s_beg; s < s_end - 1; ++s) {
    // prefetch s+1 (always in-bounds: s+1 <= s_end-1 <= 624)
    float4 v0 = *(const float4*)(arow0 + (size_t)(s + 1) * 32);
    float4 v1 = *(const float4*)(arow0 + (size_t)(s + 1) * 32 + 4);
    float4 v2 = *(const float4*)(arow1 + (size_t)(s + 1) * 32);
    float4 v3 = *(const float4*)(arow1 + (size_t)(s + 1) * 32 + 4);
    const unsigned short* bpn = bp + 8192;
    short8 bn[4];
#pragma unroll
    for (int nt = 0; nt < 4; ++nt) bn[nt] = *(const short8*)(bpn + nt * 512);

    uint4 af0 = make_uint4(pk2bf(u0.x, u0.y), pk2bf(u0.z, u0.w), pk2bf(u1.x, u1.y), pk2bf(u1.z, u1.w));
    uint4 af1 = make_uint4(pk2bf(u2.x, u2.y), pk2bf(u2.z, u2.w), pk2bf(u3.x, u3.y), pk2bf(u3.z, u3.w));
    short8 a0 = *(short8*)&af0;
    short8 a1 = *(short8*)&af1;
#pragma unroll
    for (int nt = 0; nt < 4; ++nt) {
      acc[0][nt] = __builtin_amdgcn_mfma_f32_16x16x32_bf16(a0, bc[nt], acc[0][nt], 0, 0, 0);
      acc[1][nt] = __builtin_amdgcn_mfma_f32_16x16x32_bf16(a1, bc[nt], acc[1][nt], 0, 0, 0);
    }
    u0 = v0; u1 = v1; u2 = v2; u3 = v3;
#pragma unroll
    for (int nt = 0; nt < 4; ++nt) bc[nt] = bn[nt];
    bp = bpn;
  }
  {  // last step
    uint4 af0 = make_uint4(pk2bf(u0.x, u0.y), pk2bf(u0.z, u0.w), pk2bf(u1.x, u1.y), pk2bf(u1.z, u1.w));
    uint4 af1 = make_uint4(pk2bf(u2.x, u2.y), pk2bf(u2.z, u2.w), pk2bf(u3.x, u3.y), pk2bf(u3.z, u3.w));
    short8 a0 = *(short8*)&af0;
    short8 a1 = *(short8*)&af1;
#pragma unroll
    for (int nt = 0; nt < 4; ++nt) {
      acc[0][nt] = __builtin_amdgcn_mfma_f32_16x16x32_bf16(a0, bc[nt], acc[0][nt], 0, 0, 0);
      acc[1][nt] = __builtin_amdgcn_mfma_f32_16x16x32_bf16(a1, bc[nt], acc[1][nt], 0, 0, 0);
    }
  }

  float* outp = h0p + (size_t)split * (N_NODES * HIDDEN) + (size_t)m0 * HIDDEN;
#pragma unroll
  for (int mt = 0; mt < 2; ++mt)
#pragma unroll
    for (int nt = 0; nt < 4; ++nt) {
      int col = wn * 64 + nt * 16 + lr;
#pragma unroll
      for (int r = 0; r < 4; ++r) {
        int rowi = mt * 16 + lg * 4 + r;
        outp[rowi * HIDDEN + col] = acc[mt][nt][r];
      }
    }
}

__global__ void k_sum(const float* __restrict__ p, float* __restrict__ h0) {
  int i = blockIdx.x * 256 + threadIdx.x;
  float4 a = ((const float4*)p)[i];
  float4 b = ((const float4*)p)[i + (N_NODES * HIDDEN / 4)];
  float4 c = ((const float4*)p)[i + 2 * (N_NODES * HIDDEN / 4)];
  float4 d = ((const float4*)p)[i + 3 * (N_NODES * HIDDEN / 4)];
  float4 r;
  r.x = (a.x + b.x) + (c.x + d.x);
  r.y = (a.y + b.y) + (c.y + d.y);
  r.z = (a.z + b.z) + (c.z + d.z);
  r.w = (a.w + b.w) + (c.w + d.w);
  ((float4*)h0)[i] = r;
}

// ------------- GCN aggregate (CSR gather) + bias + relu -------------
__global__ void k_agg(const float* __restrict__ h0, const float* __restrict__ dinv,
                      const int* __restrict__ offs, const int* __restrict__ csr_src,
                      const float* __restrict__ bias, float* __restrict__ hrelu) {
  int c = blockIdx.x;
  int t = threadIdx.x;
  float dc = dinv[c];
  float acc = h0[(size_t)c * HIDDEN + t] * dc * dc;  // self loop
  int beg = offs[c], end = offs[c + 1];
  for (int i = beg; i < end; ++i) {
    int r = csr_src[i];
    float wgt = dinv[r] * dc;
    acc += h0[(size_t)r * HIDDEN + t] * wgt;
  }
  float v = acc + bias[t];
  hrelu[(size_t)c * HIDDEN + t] = v > 0.f ? v : 0.f;
}

// ------------- encoder: latent = relu_h @ w_enc + b_enc (fp32) -------------
__global__ void k_enc(const float* __restrict__ hrelu, const float* __restrict__ w_enc,
                      const float* __restrict__ b_enc, float* __restrict__ latent) {
  __shared__ float hrow[4 * HIDDEN];
  int nb = blockIdx.x * 4;
  int t = threadIdx.x;
#pragma unroll
  for (int j = 0; j < 4; ++j) hrow[j * HIDDEN + t] = hrelu[(size_t)(nb + j) * HIDDEN + t];
  __syncthreads();
  int lat = t & 63;
  int nl = t >> 6;
  float acc = b_enc[lat];
#pragma unroll 8
  for (int k = 0; k < HIDDEN; ++k)
    acc += hrow[nl * HIDDEN + k] * w_enc[k * LATENT + lat];
  latent[(size_t)(nb + nl) * LATENT + lat] = acc;
}

// ------------- decoder L1: hid2 = bf16(relu(latent @ w_d1 + b_d1)) -------------
__global__ void k_dec1(const float* __restrict__ latent, const float* __restrict__ w_d1,
                       const float* __restrict__ b_d1, unsigned short* __restrict__ hid2) {
  __shared__ float lrow[4 * LATENT];
  int nb = blockIdx.x * 4;
  int t = threadIdx.x;
  lrow[t] = latent[(size_t)nb * LATENT + t];  // 4*64 == 256 threads
  __syncthreads();
  float b = b_d1[t];
  float a0 = b, a1 = b, a2 = b, a3 = b;
#pragma unroll 8
  for (int k = 0; k < LATENT; ++k) {
    float wv = w_d1[k * HIDDEN + t];
    a0 += lrow[k] * wv;
    a1 += lrow[LATENT + k] * wv;
    a2 += lrow[2 * LATENT + k] * wv;
    a3 += lrow[3 * LATENT + k] * wv;
  }
  hid2[(size_t)nb * HIDDEN + t]       = f2bf(a0 > 0.f ? a0 : 0.f);
  hid2[(size_t)(nb + 1) * HIDDEN + t] = f2bf(a1 > 0.f ? a1 : 0.f);
  hid2[(size_t)(nb + 2) * HIDDEN + t] = f2bf(a2 > 0.f ? a2 : 0.f);
  hid2[(size_t)(nb + 3) * HIDDEN + t] = f2bf(a3 > 0.f ? a3 : 0.f);
}

// ------------- GEMM3: recon = hid2 @ w_d2 + b_d2 (bf16 MFMA, K=256) -------------
// Persistent m-panel (128 rows), 32-col subtiles, 4 waves (wave = 32r x 32c).
// NO barriers: A in regs (64 VGPR), B fragments direct from global (L1/L2-served,
// one-deep prefetch), per-wave LDS transpose (wave-internal lgkm only) ->
// 128B-segment float4 stores. grid (64,16), 256 thr.
__global__ __launch_bounds__(256, 3)
void k_gemm3(const unsigned short* __restrict__ hid2, const unsigned short* __restrict__ wd2f,
             const float* __restrict__ b_d2, float* __restrict__ recon) {
  __shared__ float TB[4 * 512];  // per-wave 16x32 transpose buf, 8KB
  const int t = threadIdx.x;
  const int lane = t & 63;
  const int wid = t >> 6;    // 0..3: m-group of 32 rows
  const int lr = lane & 15;
  const int lg = lane >> 4;
  const int m0 = blockIdx.x * 128;
  const int chunk = blockIdx.y;
  const int s0 = (NSUB3 * chunk) >> 4;
  const int s1 = (NSUB3 * (chunk + 1)) >> 4;

  // ---- A preload into registers: wave's 32 rows x K=256 (64 VGPR) ----
  short8 a[2][8];
#pragma unroll
  for (int mt = 0; mt < 2; ++mt)
#pragma unroll
    for (int ks = 0; ks < 8; ++ks)
      a[mt][ks] = *(const short8*)(hid2 + (size_t)(m0 + wid * 32 + mt * 16 + lr) * 256 + ks * 32 + lg * 8);

  // B fragment stream: linear in f = sub*8+ks; lane offset lr*32+lg*8, nt at +512
  const unsigned short* bp = wd2f + ((size_t)s0 * 8 * 32 + lr) * 32 + lg * 8;
  short8 bc0 = *(const short8*)bp;
  short8 bc1 = *(const short8*)(bp + 512);

  for (int sub = s0; sub < s1; ++sub) {
    f32x4 acc[2][2];
#pragma unroll
    for (int i = 0; i < 2; ++i) {
      acc[i][0] = (f32x4){0.f, 0.f, 0.f, 0.f};
      acc[i][1] = (f32x4){0.f, 0.f, 0.f, 0.f};
    }
#pragma unroll
    for (int ks = 0; ks < 8; ++ks) {
      // prefetch next fragment pair (last one overruns into next ws buffer
      // by <2KB: mapped, value unused, harmless)
      const unsigned short* bpn = bp + 1024;
      short8 bn0 = *(const short8*)bpn;
      short8 bn1 = *(const short8*)(bpn + 512);
#pragma unroll
      for (int mt = 0; mt < 2; ++mt) {
        acc[mt][0] = __builtin_amdgcn_mfma_f32_16x16x32_bf16(a[mt][ks], bc0, acc[mt][0], 0, 0, 0);
        acc[mt][1] = __builtin_amdgcn_mfma_f32_16x16x32_bf16(a[mt][ks], bc1, acc[mt][1], 0, 0, 0);
      }
      bc0 = bn0; bc1 = bn1; bp = bpn;
    }

    // ---- epilogue: per-wave LDS transpose -> coalesced float4 stores ----
    const int cg = (lane & 7) * 4;
    const int gc = sub * 32 + cg;
    f32x4 bias4 = (f32x4){0.f, 0.f, 0.f, 0.f};
    if (gc < IN_DIM) bias4 = *(const f32x4*)&b_d2[gc];
    float* TBw = TB + wid * 512;
#pragma unroll
    for (int mt = 0; mt < 2; ++mt) {
#pragma unroll
      for (int nt = 0; nt < 2; ++nt)
#pragma unroll
        for (int r = 0; r < 4; ++r) {
          int row = lg * 4 + r;
          TBw[row * 32 + ((nt * 16 + lr) ^ (((row >> 2) & 1) << 4))] = acc[mt][nt][r];
        }
#pragma unroll
      for (int p = 0; p < 2; ++p) {
        int row = p * 8 + (lane >> 3);
        f32x4 v = *(const f32x4*)&TBw[row * 32 + (cg ^ (((row >> 2) & 1) << 4))];
        if (gc < IN_DIM) {
          int gr = m0 + wid * 32 + mt * 16 + row;
          *(f32x4*)&recon[(size_t)gr * IN_DIM + gc] = v + bias4;
        }
      }
    }
  }
}

extern "C" void kernel_launch(void* const* d_in, const int* in_sizes, int n_in,
                              void* d_out, int out_size, void* d_ws, size_t ws_size,
                              hipStream_t stream) {
  const float* x     = (const float*)d_in[0];
  const int*   edge  = (const int*)d_in[1];
  const float* w_gcn = (const float*)d_in[2];
  const float* b_gcn = (const float*)d_in[3];
  const float* w_enc = (const float*)d_in[4];
  const float* b_enc = (const float*)d_in[5];
  const float* w_d1  = (const float*)d_in[6];
  const float* b_d1  = (const float*)d_in[7];
  const float* w_d2  = (const float*)d_in[8];
  const float* b_d2  = (const float*)d_in[9];
  float* out = (float*)d_out;
  (void)in_sizes; (void)n_in; (void)out_size; (void)ws_size;

  char* ws = (char*)d_ws;
  size_t o = 0;
  auto alloc = [&](size_t bytes) {
    char* p = ws + o;
    o += (bytes + 255) & ~(size_t)255;
    return p;
  };
  unsigned short* wpk  = (unsigned short*)alloc((size_t)K_STEPS * HIDDEN * 32 * 2);
  unsigned short* wd2f = (unsigned short*)alloc((size_t)NSUB3 * 8 * 32 * 32 * 2);
  float* h0p  = (float*)alloc((size_t)4 * N_NODES * HIDDEN * 4);
  float* h0   = (float*)alloc((size_t)N_NODES * HIDDEN * 4);
  float* hrel = (float*)alloc((size_t)N_NODES * HIDDEN * 4);
  unsigned short* hid2 = (unsigned short*)alloc((size_t)N_NODES * HIDDEN * 2);
  int* cnt    = (int*)alloc(N_NODES * 4);
  float* dinv = (float*)alloc(N_NODES * 4);
  int* offs   = (int*)alloc((N_NODES + 1) * 4);
  int* cursor = (int*)alloc(N_NODES * 4);
  int* csr    = (int*)alloc((size_t)N_EDGES * 4);

  const int* erow = edge;
  const int* ecol = edge + N_EDGES;

  hipMemsetAsync(cnt, 0, N_NODES * 4, stream);
  k_count<<<N_EDGES / 256, 256, 0, stream>>>(ecol, cnt);
  k_scan<<<1, 256, 0, stream>>>(cnt, offs, cursor);
  k_dinv<<<N_NODES / 256, 256, 0, stream>>>(cnt, dinv);
  k_fill<<<N_EDGES / 256, 256, 0, stream>>>(erow, ecol, cursor, csr);
  k_pack_wgcn<<<K_STEPS, 256, 0, stream>>>(w_gcn, wpk);
  k_pack_wd2f<<<NSUB3, 256, 0, stream>>>(w_d2, wd2f);
  k_gemm1<<<dim3(N_NODES / 32, 4), 256, 0, stream>>>(x, wpk, h0p);
  k_sum<<<(N_NODES * HIDDEN / 4) / 256, 256, 0, stream>>>(h0p, h0);
  k_agg<<<N_NODES, 256, 0, stream>>>(h0, dinv, offs, csr, b_gcn, hrel);
  float* latent = out + RECON_ELEMS;
  k_enc<<<N_NODES / 4, 256, 0, stream>>>(hrel, w_enc, b_enc, latent);
  k_dec1<<<N_NODES / 4, 256, 0, stream>>>(latent, w_d1, b_d1, hid2);
  k_gemm3<<<dim3(N_NODES / 128, 16), 256, 0, stream>>>(hid2, wd2f, b_d2, out);
}

// Round 6
// 635.731 us; speedup vs baseline: 1.4983x; 1.4983x over previous
//
#include <hip/hip_runtime.h>
#include <stdint.h>

typedef short short8 __attribute__((ext_vector_type(8)));
typedef float f32x4 __attribute__((ext_vector_type(4)));

#define N_NODES 8192
#define IN_DIM 20000
#define HIDDEN 256
#define LATENT 64
#define N_EDGES 262144
#define K_STEPS 625
#define RECON_ELEMS (8192LL * 20000LL)
#define WD2T_ROWS 20096
#define NSUB3 626   // 32-col subtiles covering 20032 >= 20000 cols

static __device__ __forceinline__ unsigned short f2bf(float f) {
  union { float f; unsigned int u; } v;
  v.f = f;
  unsigned int u = v.u;
  return (unsigned short)((u + 0x7FFFu + ((u >> 16) & 1u)) >> 16);  // RNE
}

static __device__ __forceinline__ unsigned pk2bf(float a, float b) {
  return (unsigned)f2bf(a) | ((unsigned)f2bf(b) << 16);
}

// ----------------- graph prep: degree, scan, CSR fill -----------------
__global__ void k_count(const int* __restrict__ col, int* __restrict__ cnt) {
  int e = blockIdx.x * 256 + threadIdx.x;
  if (e < N_EDGES) atomicAdd(&cnt[col[e]], 1);
}

__global__ void k_dinv(const int* __restrict__ cnt, float* __restrict__ dinv) {
  int i = blockIdx.x * 256 + threadIdx.x;
  if (i < N_NODES) dinv[i] = rsqrtf((float)(cnt[i] + 1));  // +1 self loop
}

__global__ void k_scan(const int* __restrict__ cnt, int* __restrict__ offs,
                       int* __restrict__ cursor) {
  __shared__ int ps[256];
  int t = threadIdx.x;
  int local[32];
  int s = 0;
#pragma unroll
  for (int i = 0; i < 32; ++i) { local[i] = cnt[t * 32 + i]; s += local[i]; }
  ps[t] = s;
  __syncthreads();
  for (int d = 1; d < 256; d <<= 1) {
    int v = (t >= d) ? ps[t - d] : 0;
    __syncthreads();
    ps[t] += v;
    __syncthreads();
  }
  int pre = (t == 0) ? 0 : ps[t - 1];
#pragma unroll
  for (int i = 0; i < 32; ++i) {
    offs[t * 32 + i] = pre;
    cursor[t * 32 + i] = pre;
    pre += local[i];
  }
  if (t == 255) offs[N_NODES] = pre;
}

__global__ void k_fill(const int* __restrict__ row, const int* __restrict__ col,
                       int* __restrict__ cursor, int* __restrict__ csr_src) {
  int e = blockIdx.x * 256 + threadIdx.x;
  if (e < N_EDGES) {
    int c = col[e];
    int pos = atomicAdd(&cursor[c], 1);
    csr_src[pos] = row[e];
  }
}

// ------- pack w_gcn [20000][256] f32 -> [kstep][n=256][k=32] bf16 (linear) ---
__global__ void k_pack_wgcn(const float* __restrict__ w, unsigned short* __restrict__ pk) {
  int s = blockIdx.x;   // 625 k-steps
  int t = threadIdx.x;  // n = t
  int k0 = s * 32;
  unsigned int packed[16];
#pragma unroll
  for (int j = 0; j < 16; ++j) {
    float a = w[(size_t)(k0 + 2 * j) * HIDDEN + t];
    float b = w[(size_t)(k0 + 2 * j + 1) * HIDDEN + t];
    packed[j] = pk2bf(a, b);
  }
  uint4* dst = (uint4*)(pk + ((size_t)s * HIDDEN + t) * 32);
#pragma unroll
  for (int j = 0; j < 4; ++j)
    dst[j] = make_uint4(packed[4 * j], packed[4 * j + 1], packed[4 * j + 2], packed[4 * j + 3]);
}

// ------- transpose w_d2 [256][20000] f32 -> [20096][256] bf16, zero-padded,
// ------- with 16B-chunk XOR swizzle (chunk c -> c ^ (row&7)) baked in  -------
__global__ void k_twd2(const float* __restrict__ wd2, unsigned short* __restrict__ wd2t) {
  __shared__ float tile[HIDDEN * 64];  // [k][n_local], 64 KB
  int n0 = blockIdx.x * 64;            // 314 blocks
  int t = threadIdx.x;
  int tk = t >> 6;   // 0..3
  int tn = t & 63;
#pragma unroll 4
  for (int kb = 0; kb < 64; ++kb) {
    int k = kb * 4 + tk;
    int n = n0 + tn;
    tile[k * 64 + tn] = (n < IN_DIM) ? wd2[(size_t)k * IN_DIM + n] : 0.0f;
  }
  __syncthreads();
  int rl = t >> 2;   // out row local 0..63
  int q = t & 3;     // k quarter
  unsigned int packed[32];
#pragma unroll
  for (int j = 0; j < 32; ++j) {
    float a = tile[(q * 64 + 2 * j) * 64 + rl];
    float b = tile[(q * 64 + 2 * j + 1) * 64 + rl];
    packed[j] = pk2bf(a, b);
  }
  int rs = rl & 7;   // (n0+rl)&7 == rl&7 since n0 % 64 == 0
  uint4* dst = (uint4*)(wd2t + (size_t)(n0 + rl) * HIDDEN + q * 64);
#pragma unroll
  for (int j = 0; j < 8; ++j)
    dst[j ^ rs] = make_uint4(packed[4 * j], packed[4 * j + 1], packed[4 * j + 2], packed[4 * j + 3]);
}

// ----------------- GEMM1: h0p[split] = x @ w_gcn (bf16 MFMA) -----------------
// BM=32 BN=256, macro-step BK=128 (512B/row sequential DRAM runs), split-K=4
// pinned per-XCD (B slice L2-resident). A staged via 2x8KB rotation-swizzled
// LDS; B fragment-direct from global. grid 1024 linear, 256 thr, 4 blocks/CU.
__global__ __launch_bounds__(256, 4)
void k_gemm1(const float* __restrict__ x, const unsigned short* __restrict__ wpk,
             float* __restrict__ h0p) {
  const int wgid = blockIdx.x;
  const int xcd = wgid & 7;
  const int split = xcd >> 1;                           // XCD pair -> split
  const int m0 = (((wgid >> 3) << 1) | (xcd & 1)) << 5; // m-block
  const int s_beg = split * 156;                        // 39 macros x 4 k32

  const int t = threadIdx.x;
  const int lane = t & 63;
  const int wn = t >> 6;     // 0..3: 64-col group
  const int lr = lane & 15;
  const int lg = lane >> 4;

  __shared__ unsigned short Al[2][32 * 128];  // [row][k128] bf16, row-rotated 16B chunks

  // A staging: thread (r, c8) reads row m0+r, 16B at k = c8*4 + j*32 (+macro*128)
  const int r = t >> 3;
  const int c8 = t & 7;
  const float* ap = x + (size_t)(m0 + r) * IN_DIM + s_beg * 32 + c8 * 4;

  auto wrA = [&](int buf, const float4* u) {
#pragma unroll
    for (int j = 0; j < 4; ++j) {
      int cc = (c8 >> 1) + j * 4;                       // 16B chunk index 0..15
      int idx = r * 128 + (((cc + r) & 15) << 3) + ((c8 & 1) << 2);
      *(uint2*)&Al[buf][idx] = make_uint2(pk2bf(u[j].x, u[j].y), pk2bf(u[j].z, u[j].w));
    }
  };

  // B fragment pointer (linear wpk [step][n][k])
  const unsigned short* bq = wpk + ((size_t)s_beg * HIDDEN + wn * 64 + lr) * 32 + lg * 8;

  f32x4 acc[2][4];
#pragma unroll
  for (int i = 0; i < 2; ++i)
#pragma unroll
    for (int j = 0; j < 4; ++j) acc[i][j] = (f32x4){0.f, 0.f, 0.f, 0.f};

  {  // prologue: stage macro 0
    float4 u[4];
#pragma unroll
    for (int j = 0; j < 4; ++j) u[j] = *(const float4*)(ap + j * 32);
    wrA(0, u);
  }
  __syncthreads();

  int cur = 0;
  for (int mi = 0; mi < 39; ++mi) {
    float4 v[4];
    if (mi < 38) {
#pragma unroll
      for (int j = 0; j < 4; ++j)
        v[j] = *(const float4*)(ap + (mi + 1) * 128 + j * 32);
    }
#pragma unroll
    for (int ks = 0; ks < 4; ++ks) {
      short8 b0 = *(const short8*)(bq);
      short8 b1 = *(const short8*)(bq + 512);
      short8 b2 = *(const short8*)(bq + 1024);
      short8 b3 = *(const short8*)(bq + 1536);
      const int cra = (((ks * 4 + lg) + lr) & 15) << 3;
      short8 a0 = *(const short8*)&Al[cur][lr * 128 + cra];
      short8 a1 = *(const short8*)&Al[cur][(16 + lr) * 128 + cra];
      acc[0][0] = __builtin_amdgcn_mfma_f32_16x16x32_bf16(a0, b0, acc[0][0], 0, 0, 0);
      acc[1][0] = __builtin_amdgcn_mfma_f32_16x16x32_bf16(a1, b0, acc[1][0], 0, 0, 0);
      acc[0][1] = __builtin_amdgcn_mfma_f32_16x16x32_bf16(a0, b1, acc[0][1], 0, 0, 0);
      acc[1][1] = __builtin_amdgcn_mfma_f32_16x16x32_bf16(a1, b1, acc[1][1], 0, 0, 0);
      acc[0][2] = __builtin_amdgcn_mfma_f32_16x16x32_bf16(a0, b2, acc[0][2], 0, 0, 0);
      acc[1][2] = __builtin_amdgcn_mfma_f32_16x16x32_bf16(a1, b2, acc[1][2], 0, 0, 0);
      acc[0][3] = __builtin_amdgcn_mfma_f32_16x16x32_bf16(a0, b3, acc[0][3], 0, 0, 0);
      acc[1][3] = __builtin_amdgcn_mfma_f32_16x16x32_bf16(a1, b3, acc[1][3], 0, 0, 0);
      bq += HIDDEN * 32;
    }
    __syncthreads();                 // reads of Al[cur] complete
    if (mi < 38) wrA(cur ^ 1, v);
    __syncthreads();                 // writes visible
    cur ^= 1;
  }

  if (split == 3) {  // tail k32-step s=624, reg-direct
    const float* a0p = x + (size_t)(m0 + lr) * IN_DIM + 624 * 32 + lg * 8;
    const float* a1p = x + (size_t)(m0 + 16 + lr) * IN_DIM + 624 * 32 + lg * 8;
    float4 w0 = *(const float4*)a0p, w1 = *(const float4*)(a0p + 4);
    float4 w2 = *(const float4*)a1p, w3 = *(const float4*)(a1p + 4);
    uint4 af0 = make_uint4(pk2bf(w0.x, w0.y), pk2bf(w0.z, w0.w), pk2bf(w1.x, w1.y), pk2bf(w1.z, w1.w));
    uint4 af1 = make_uint4(pk2bf(w2.x, w2.y), pk2bf(w2.z, w2.w), pk2bf(w3.x, w3.y), pk2bf(w3.z, w3.w));
    short8 a0 = *(short8*)&af0;
    short8 a1 = *(short8*)&af1;
    // bq now points at step 624
    short8 b0 = *(const short8*)(bq);
    short8 b1 = *(const short8*)(bq + 512);
    short8 b2 = *(const short8*)(bq + 1024);
    short8 b3 = *(const short8*)(bq + 1536);
    acc[0][0] = __builtin_amdgcn_mfma_f32_16x16x32_bf16(a0, b0, acc[0][0], 0, 0, 0);
    acc[1][0] = __builtin_amdgcn_mfma_f32_16x16x32_bf16(a1, b0, acc[1][0], 0, 0, 0);
    acc[0][1] = __builtin_amdgcn_mfma_f32_16x16x32_bf16(a0, b1, acc[0][1], 0, 0, 0);
    acc[1][1] = __builtin_amdgcn_mfma_f32_16x16x32_bf16(a1, b1, acc[1][1], 0, 0, 0);
    acc[0][2] = __builtin_amdgcn_mfma_f32_16x16x32_bf16(a0, b2, acc[0][2], 0, 0, 0);
    acc[1][2] = __builtin_amdgcn_mfma_f32_16x16x32_bf16(a1, b2, acc[1][2], 0, 0, 0);
    acc[0][3] = __builtin_amdgcn_mfma_f32_16x16x32_bf16(a0, b3, acc[0][3], 0, 0, 0);
    acc[1][3] = __builtin_amdgcn_mfma_f32_16x16x32_bf16(a1, b3, acc[1][3], 0, 0, 0);
  }

  float* outp = h0p + (size_t)split * (N_NODES * HIDDEN) + (size_t)m0 * HIDDEN;
#pragma unroll
  for (int mt = 0; mt < 2; ++mt)
#pragma unroll
    for (int nt = 0; nt < 4; ++nt) {
      int col = wn * 64 + nt * 16 + lr;
#pragma unroll
      for (int rr = 0; rr < 4; ++rr) {
        int rowi = mt * 16 + lg * 4 + rr;
        outp[rowi * HIDDEN + col] = acc[mt][nt][rr];
      }
    }
}

__global__ void k_sum(const float* __restrict__ p, float* __restrict__ h0) {
  int i = blockIdx.x * 256 + threadIdx.x;
  float4 a = ((const float4*)p)[i];
  float4 b = ((const float4*)p)[i + (N_NODES * HIDDEN / 4)];
  float4 c = ((const float4*)p)[i + 2 * (N_NODES * HIDDEN / 4)];
  float4 d = ((const float4*)p)[i + 3 * (N_NODES * HIDDEN / 4)];
  float4 r;
  r.x = (a.x + b.x) + (c.x + d.x);
  r.y = (a.y + b.y) + (c.y + d.y);
  r.z = (a.z + b.z) + (c.z + d.z);
  r.w = (a.w + b.w) + (c.w + d.w);
  ((float4*)h0)[i] = r;
}

// ------------- GCN aggregate (CSR gather) + bias + relu -------------
__global__ void k_agg(const float* __restrict__ h0, const float* __restrict__ dinv,
                      const int* __restrict__ offs, const int* __restrict__ csr_src,
                      const float* __restrict__ bias, float* __restrict__ hrelu) {
  int c = blockIdx.x;
  int t = threadIdx.x;
  float dc = dinv[c];
  float acc = h0[(size_t)c * HIDDEN + t] * dc * dc;  // self loop
  int beg = offs[c], end = offs[c + 1];
  for (int i = beg; i < end; ++i) {
    int r = csr_src[i];
    float wgt = dinv[r] * dc;
    acc += h0[(size_t)r * HIDDEN + t] * wgt;
  }
  float v = acc + bias[t];
  hrelu[(size_t)c * HIDDEN + t] = v > 0.f ? v : 0.f;
}

// ------------- encoder: latent = relu_h @ w_enc + b_enc (fp32) -------------
__global__ void k_enc(const float* __restrict__ hrelu, const float* __restrict__ w_enc,
                      const float* __restrict__ b_enc, float* __restrict__ latent) {
  __shared__ float hrow[4 * HIDDEN];
  int nb = blockIdx.x * 4;
  int t = threadIdx.x;
#pragma unroll
  for (int j = 0; j < 4; ++j) hrow[j * HIDDEN + t] = hrelu[(size_t)(nb + j) * HIDDEN + t];
  __syncthreads();
  int lat = t & 63;
  int nl = t >> 6;
  float acc = b_enc[lat];
#pragma unroll 8
  for (int k = 0; k < HIDDEN; ++k)
    acc += hrow[nl * HIDDEN + k] * w_enc[k * LATENT + lat];
  latent[(size_t)(nb + nl) * LATENT + lat] = acc;
}

// ------------- decoder L1: hid2 = bf16(relu(latent @ w_d1 + b_d1)) -------------
__global__ void k_dec1(const float* __restrict__ latent, const float* __restrict__ w_d1,
                       const float* __restrict__ b_d1, unsigned short* __restrict__ hid2) {
  __shared__ float lrow[4 * LATENT];
  int nb = blockIdx.x * 4;
  int t = threadIdx.x;
  lrow[t] = latent[(size_t)nb * LATENT + t];  // 4*64 == 256 threads
  __syncthreads();
  float b = b_d1[t];
  float a0 = b, a1 = b, a2 = b, a3 = b;
#pragma unroll 8
  for (int k = 0; k < LATENT; ++k) {
    float wv = w_d1[k * HIDDEN + t];
    a0 += lrow[k] * wv;
    a1 += lrow[LATENT + k] * wv;
    a2 += lrow[2 * LATENT + k] * wv;
    a3 += lrow[3 * LATENT + k] * wv;
  }
  hid2[(size_t)nb * HIDDEN + t]       = f2bf(a0 > 0.f ? a0 : 0.f);
  hid2[(size_t)(nb + 1) * HIDDEN + t] = f2bf(a1 > 0.f ? a1 : 0.f);
  hid2[(size_t)(nb + 2) * HIDDEN + t] = f2bf(a2 > 0.f ? a2 : 0.f);
  hid2[(size_t)(nb + 3) * HIDDEN + t] = f2bf(a3 > 0.f ? a3 : 0.f);
}

// ------------- GEMM3: recon = hid2 @ w_d2 + b_d2 (bf16 MFMA, K=256) -------------
// R4 design: persistent m-panel (128 rows), 32-col subtiles, 4 waves (32r x 32c),
// A in regs, B dbuf LDS via glds (pre-swizzled wd2t), LDS-transpose epilogue,
// XCD-pinned column chunks. grid 1024 linear, 256 thr, 40KB LDS -> 4 blocks/CU.
__global__ __launch_bounds__(256, 4)
void k_gemm3(const unsigned short* __restrict__ hid2, const unsigned short* __restrict__ wd2t,
             const float* __restrict__ b_d2, float* __restrict__ recon) {
  __shared__ unsigned short Bl[2][32 * 256];  // 2 x 16KB
  __shared__ float TB[4 * 512];               // per-wave transpose buf, 8KB
  const int wgid = blockIdx.x;
  const int chunk = ((wgid & 7) << 1) | (wgid >> 9);   // XCD-pinned chunk
  const int m0 = ((wgid >> 3) & 63) * 128;
  const int t = threadIdx.x;
  const int lane = t & 63;
  const int wid = t >> 6;    // 0..3: m-group of 32 rows
  const int lr = lane & 15;
  const int lg = lane >> 4;
  const int s0 = (NSUB3 * chunk) >> 4;
  const int s1 = (NSUB3 * (chunk + 1)) >> 4;

  // ---- A preload into registers: wave's 32 rows x K=256 (64 VGPR) ----
  short8 a[2][8];
#pragma unroll
  for (int mt = 0; mt < 2; ++mt)
#pragma unroll
    for (int ks = 0; ks < 8; ++ks)
      a[mt][ks] = *(const short8*)(hid2 + (size_t)(m0 + wid * 32 + mt * 16 + lr) * 256 + ks * 32 + lg * 8);

  auto stage = [&](int sub, int buf) {
#pragma unroll
    for (int i = 0; i < 4; ++i) {
      const unsigned short* g = wd2t + (size_t)sub * (32 * 256) + ((wid * 4 + i) * 512 + lane * 8);
      unsigned short* l = &Bl[buf][(wid * 4 + i) * 512];
      __builtin_amdgcn_global_load_lds(
          (const __attribute__((address_space(1))) unsigned int*)g,
          (__attribute__((address_space(3))) unsigned int*)l, 16, 0, 0);
    }
  };

  stage(s0, 0);
  __syncthreads();

  int cur = 0;
  for (int sub = s0; sub < s1; ++sub) {
    if (sub + 1 < s1) stage(sub + 1, cur ^ 1);

    f32x4 acc[2][2];
#pragma unroll
    for (int i = 0; i < 2; ++i) {
      acc[i][0] = (f32x4){0.f, 0.f, 0.f, 0.f};
      acc[i][1] = (f32x4){0.f, 0.f, 0.f, 0.f};
    }

    const int rl0 = lr;
    const int rl1 = 16 + lr;
#pragma unroll
    for (int ks = 0; ks < 8; ++ks) {
      short8 b0 = *(const short8*)&Bl[cur][rl0 * 256 + (((ks * 4 + lg) ^ (rl0 & 7)) << 3)];
      short8 b1 = *(const short8*)&Bl[cur][rl1 * 256 + (((ks * 4 + lg) ^ (rl1 & 7)) << 3)];
#pragma unroll
      for (int mt = 0; mt < 2; ++mt) {
        acc[mt][0] = __builtin_amdgcn_mfma_f32_16x16x32_bf16(a[mt][ks], b0, acc[mt][0], 0, 0, 0);
        acc[mt][1] = __builtin_amdgcn_mfma_f32_16x16x32_bf16(a[mt][ks], b1, acc[mt][1], 0, 0, 0);
      }
    }

    // ---- epilogue: per-wave LDS transpose -> coalesced float4 stores ----
    const int cg = (lane & 7) * 4;
    const int gc = sub * 32 + cg;
    f32x4 bias4 = (f32x4){0.f, 0.f, 0.f, 0.f};
    if (gc < IN_DIM) bias4 = *(const f32x4*)&b_d2[gc];
    float* TBw = TB + wid * 512;
#pragma unroll
    for (int mt = 0; mt < 2; ++mt) {
#pragma unroll
      for (int nt = 0; nt < 2; ++nt)
#pragma unroll
        for (int rr = 0; rr < 4; ++rr) {
          int row = lg * 4 + rr;
          TBw[row * 32 + ((nt * 16 + lr) ^ (((row >> 2) & 1) << 4))] = acc[mt][nt][rr];
        }
#pragma unroll
      for (int p = 0; p < 2; ++p) {
        int row = p * 8 + (lane >> 3);
        f32x4 v = *(const f32x4*)&TB[wid * 512 + row * 32 + (cg ^ (((row >> 2) & 1) << 4))];
        if (gc < IN_DIM) {
          int gr = m0 + wid * 32 + mt * 16 + row;
          *(f32x4*)&recon[(size_t)gr * IN_DIM + gc] = v + bias4;
        }
      }
    }
    __syncthreads();
    cur ^= 1;
  }
}

extern "C" void kernel_launch(void* const* d_in, const int* in_sizes, int n_in,
                              void* d_out, int out_size, void* d_ws, size_t ws_size,
                              hipStream_t stream) {
  const float* x     = (const float*)d_in[0];
  const int*   edge  = (const int*)d_in[1];
  const float* w_gcn = (const float*)d_in[2];
  const float* b_gcn = (const float*)d_in[3];
  const float* w_enc = (const float*)d_in[4];
  const float* b_enc = (const float*)d_in[5];
  const float* w_d1  = (const float*)d_in[6];
  const float* b_d1  = (const float*)d_in[7];
  const float* w_d2  = (const float*)d_in[8];
  const float* b_d2  = (const float*)d_in[9];
  float* out = (float*)d_out;
  (void)in_sizes; (void)n_in; (void)out_size; (void)ws_size;

  char* ws = (char*)d_ws;
  size_t o = 0;
  auto alloc = [&](size_t bytes) {
    char* p = ws + o;
    o += (bytes + 255) & ~(size_t)255;
    return p;
  };
  unsigned short* wpk  = (unsigned short*)alloc((size_t)K_STEPS * HIDDEN * 32 * 2);
  unsigned short* wd2t = (unsigned short*)alloc((size_t)WD2T_ROWS * HIDDEN * 2);
  float* h0p  = (float*)alloc((size_t)4 * N_NODES * HIDDEN * 4);
  float* h0   = (float*)alloc((size_t)N_NODES * HIDDEN * 4);
  float* hrel = (float*)alloc((size_t)N_NODES * HIDDEN * 4);
  unsigned short* hid2 = (unsigned short*)alloc((size_t)N_NODES * HIDDEN * 2);
  int* cnt    = (int*)alloc(N_NODES * 4);
  float* dinv = (float*)alloc(N_NODES * 4);
  int* offs   = (int*)alloc((N_NODES + 1) * 4);
  int* cursor = (int*)alloc(N_NODES * 4);
  int* csr    = (int*)alloc((size_t)N_EDGES * 4);

  const int* erow = edge;
  const int* ecol = edge + N_EDGES;

  hipMemsetAsync(cnt, 0, N_NODES * 4, stream);
  k_count<<<N_EDGES / 256, 256, 0, stream>>>(ecol, cnt);
  k_scan<<<1, 256, 0, stream>>>(cnt, offs, cursor);
  k_dinv<<<N_NODES / 256, 256, 0, stream>>>(cnt, dinv);
  k_fill<<<N_EDGES / 256, 256, 0, stream>>>(erow, ecol, cursor, csr);
  k_pack_wgcn<<<K_STEPS, 256, 0, stream>>>(w_gcn, wpk);
  k_twd2<<<WD2T_ROWS / 64, 256, 0, stream>>>(w_d2, wd2t);
  k_gemm1<<<1024, 256, 0, stream>>>(x, wpk, h0p);
  k_sum<<<(N_NODES * HIDDEN / 4) / 256, 256, 0, stream>>>(h0p, h0);
  k_agg<<<N_NODES, 256, 0, stream>>>(h0, dinv, offs, csr, b_gcn, hrel);
  float* latent = out + RECON_ELEMS;
  k_enc<<<N_NODES / 4, 256, 0, stream>>>(hrel, w_enc, b_enc, latent);
  k_dec1<<<N_NODES / 4, 256, 0, stream>>>(latent, w_d1, b_d1, hid2);
  k_gemm3<<<1024, 256, 0, stream>>>(hid2, wd2t, b_d2, out);
}